// Round 4
// baseline (366.606 us; speedup 1.0000x reference)
//
#include <hip/hip_runtime.h>

// Problem constants (match reference)
#define NN 100000
#define TT 128
#define EE 1600000
#define KK 9
#define PADK 4
#define NSPLIT 8                  // n-splits for output matmul

// Binned CSR build
#define BSH 9                     // 512 nodes per bucket
#define BMASK 511
#define NBUCK 196                 // ceil(100000/512)
#define BCAP 10240                // avg 8163/bucket, sigma~90 -> 23 sigma headroom

typedef _Float16 f16;
typedef __attribute__((ext_vector_type(2))) _Float16 f16x2;
typedef __attribute__((ext_vector_type(4))) _Float16 f16x4;

union HU { f16x4 h; int2 i; };

// ---------- CSR build, phase 1: bin edges by dst range ----------
// Packed edge: (dlocal << 20) | src   (src < 2^17, dlocal < 2^9)
__global__ void bin_kernel(const int* __restrict__ ei, int* __restrict__ gcursor,
                           unsigned int* __restrict__ binned) {
    __shared__ int hist[NBUCK];
    __shared__ int gbase[NBUCK];
    int tid = threadIdx.x;
    for (int i = tid; i < NBUCK; i += 256) hist[i] = 0;
    __syncthreads();
    int base = blockIdx.x * 2048;
    unsigned int val[8];
    int bkt[8];
    int rank[8];
#pragma unroll
    for (int k = 0; k < 8; k++) {
        int e = base + k * 256 + tid;
        bkt[k] = -1;
        if (e < EE) {
            int s = ei[e];            // src
            int d = ei[EE + e];       // dst
            bkt[k] = d >> BSH;
            val[k] = ((unsigned int)(d & BMASK) << 20) | (unsigned int)s;
            rank[k] = atomicAdd(&hist[bkt[k]], 1);
        }
    }
    __syncthreads();
    for (int i = tid; i < NBUCK; i += 256)
        gbase[i] = hist[i] ? atomicAdd(&gcursor[i], hist[i]) : 0;
    __syncthreads();
#pragma unroll
    for (int k = 0; k < 8; k++) {
        if (bkt[k] >= 0)
            binned[(size_t)bkt[k] * BCAP + gbase[bkt[k]] + rank[k]] = val[k];
    }
}

// ---------- CSR build, phase 2a: scan bucket counts -> bucket bases ----------
__global__ void scanpart_kernel(const int* __restrict__ gcursor, int* __restrict__ part,
                                int* __restrict__ offsets) {
    __shared__ int sm[256];
    int tid = threadIdx.x;
    sm[tid] = (tid < NBUCK) ? gcursor[tid] : 0;
    __syncthreads();
    for (int off = 1; off < 256; off <<= 1) {
        int v = (tid >= off) ? sm[tid - off] : 0;
        __syncthreads();
        sm[tid] += v;
        __syncthreads();
    }
    if (tid < NBUCK) part[tid] = (tid == 0) ? 0 : sm[tid - 1];
    if (tid == 0) offsets[NN] = EE;
}

// ---------- CSR build, phase 2b: per-bucket hist + scan + offsets/inv_cnt + place ----------
__global__ void bucket_csr_kernel(const unsigned int* __restrict__ binned,
                                  const int* __restrict__ gcursor,
                                  const int* __restrict__ part,
                                  int* __restrict__ offsets,
                                  float* __restrict__ inv_cnt,
                                  int* __restrict__ col) {
    __shared__ int hist[512];
    __shared__ int cur[512];
    __shared__ int sm[256];
    int b = blockIdx.x;
    int tid = threadIdx.x;
    int cnt = gcursor[b];
    const unsigned int* ePtr = binned + (size_t)b * BCAP;
    hist[tid] = 0;
    hist[tid + 256] = 0;
    __syncthreads();
    for (int j = tid; j < cnt; j += 256)
        atomicAdd(&hist[ePtr[j] >> 20], 1);
    __syncthreads();
    // exclusive scan of 512 degree counts (thread t owns entries 2t, 2t+1)
    int d0 = hist[2 * tid], d1 = hist[2 * tid + 1];
    sm[tid] = d0 + d1;
    __syncthreads();
    for (int off = 1; off < 256; off <<= 1) {
        int v = (tid >= off) ? sm[tid - off] : 0;
        __syncthreads();
        sm[tid] += v;
        __syncthreads();
    }
    int basep = part[b] + ((tid == 0) ? 0 : sm[tid - 1]);
    int node0 = (b << BSH) + 2 * tid;
    int p0 = basep;
    int p1 = basep + d0;
    if (node0 < NN) {
        offsets[node0] = p0;
        inv_cnt[node0] = 1.0f / (1.0f + (float)d0);
        cur[2 * tid] = p0;
    }
    if (node0 + 1 < NN) {
        offsets[node0 + 1] = p1;
        inv_cnt[node0 + 1] = 1.0f / (1.0f + (float)d1);
        cur[2 * tid + 1] = p1;
    }
    __syncthreads();
    // place: all writes land in this bucket's contiguous col window (~32 KB, L2-resident)
    for (int j = tid; j < cnt; j += 256) {
        unsigned int v = ePtr[j];
        int pos = atomicAdd(&cur[v >> 20], 1);
        col[pos] = (int)(v & 0xFFFFF);
    }
}

// ---------- fp32 -> fp16 conversion of x ----------
__global__ void cvt_kernel(const float4* __restrict__ x, f16x4* __restrict__ x16) {
    int i = blockIdx.x * blockDim.x + threadIdx.x;   // over N*T/4
    float4 v = x[i];
    f16x4 o;
    o.x = (f16)v.x; o.y = (f16)v.y; o.z = (f16)v.z; o.w = (f16)v.w;
    x16[i] = o;
}

// ---------- fused layer: y = relu(conv_nobias(gather(xin)) * inv_cnt + b) ----------
// One wave per node. Lane layout: p = lane&31 owns t = {4p..4p+3} (f16x4, 8B).
// Halves of the wave process 2 edges per iteration (512B per load inst);
// accumulate in packed fp16 (v_pk_add_f16); combine halves via shfl_xor(32);
// self-loop + conv + mean + bias + relu in fp32 epilogue.
__global__ void fused_layer_kernel(const f16x4* __restrict__ xin,   // [N*32]
                                   const int* __restrict__ offsets,
                                   const int* __restrict__ col,
                                   const float* __restrict__ inv_cnt,
                                   const float* __restrict__ w9,
                                   const float* __restrict__ bptr,
                                   f16x4* __restrict__ yout) {
    int tid = threadIdx.x;
    int lane = tid & 63;
    int half = lane >> 5;
    int p = lane & 31;
    int node = blockIdx.x * 4 + (tid >> 6);

    int lo = offsets[node], hi = offsets[node + 1];
    int cnt = hi - lo;
    // lane-parallel col prefetch (one coalesced load covers deg<=64)
    int my_col = (lane < cnt) ? col[lo + lane] : 0;
    int jn = cnt < 64 ? cnt : 64;

    const f16 z = (f16)0;
    const f16 hm = half ? (f16)0 : (f16)1;
    f16x4 hmask = {hm, hm, hm, hm};
    f16x4 acc0 = {z, z, z, z};
    f16x4 acc1 = {z, z, z, z};

    int j = 0;
    for (; j + 3 < jn; j += 4) {               // 4 edges / iter
        int c0 = __shfl(my_col, j + half);
        int c1 = __shfl(my_col, j + 2 + half);
        f16x4 v0 = xin[(c0 << 5) | p];
        f16x4 v1 = xin[(c1 << 5) | p];
        acc0 += v0;
        acc1 += v1;
    }
    for (; j + 1 < jn; j += 2) {               // 2 edges
        int c = __shfl(my_col, j + half);
        acc0 += xin[(c << 5) | p];
    }
    if (j < jn) {                              // odd tail: lower half only
        int c = __shfl(my_col, j);
        acc1 += xin[(c << 5) | p] * hmask;
    }
    for (int k = 64; k < cnt; k++) {           // degree > 64 (effectively never)
        int c = col[lo + k];
        acc0 += xin[(c << 5) | p] * hmask;
    }
    acc0 += acc1;

    // combine the two halves: full-wave xor-32 shuffle of the 8-byte acc
    HU u; u.h = acc0;
    int2 o2;
    o2.x = __shfl_xor(u.i.x, 32);
    o2.y = __shfl_xor(u.i.y, 32);
    HU w; w.i = o2;
    acc0 += w.h;

    // fp32 epilogue: + self row, conv K=9, mean, bias, relu
    f16x4 sv = xin[(node << 5) | p];
    float a0 = (float)acc0.x + (float)sv.x;
    float a1 = (float)acc0.y + (float)sv.y;
    float a2 = (float)acc0.z + (float)sv.z;
    float a3 = (float)acc0.w + (float)sv.w;

    float p0 = __shfl_up(a0, 1, 32), p1 = __shfl_up(a1, 1, 32);
    float p2 = __shfl_up(a2, 1, 32), p3 = __shfl_up(a3, 1, 32);
    float n0 = __shfl_down(a0, 1, 32), n1 = __shfl_down(a1, 1, 32);
    float n2 = __shfl_down(a2, 1, 32), n3 = __shfl_down(a3, 1, 32);
    if (p == 0)  { p0 = 0.0f; p1 = 0.0f; p2 = 0.0f; p3 = 0.0f; }
    if (p == 31) { n0 = 0.0f; n1 = 0.0f; n2 = 0.0f; n3 = 0.0f; }

    float w0 = w9[0], w1 = w9[1], w2 = w9[2], w3 = w9[3], w4 = w9[4];
    float w5 = w9[5], w6 = w9[6], w7 = w9[7], w8 = w9[8];
    // out(t) = sum_k w[k] * s[t-4+k];  t = 4p + i
    float s0 = p0*w0 + p1*w1 + p2*w2 + p3*w3 + a0*w4 + a1*w5 + a2*w6 + a3*w7 + n0*w8;
    float s1 = p1*w0 + p2*w1 + p3*w2 + a0*w3 + a1*w4 + a2*w5 + a3*w6 + n0*w7 + n1*w8;
    float s2 = p2*w0 + p3*w1 + a0*w2 + a1*w3 + a2*w4 + a3*w5 + n0*w6 + n1*w7 + n2*w8;
    float s3 = p3*w0 + a0*w1 + a1*w2 + a2*w3 + a3*w4 + n0*w5 + n1*w6 + n2*w7 + n3*w8;

    float ic = inv_cnt[node];
    float b = bptr[0];
    s0 = fmaxf(s0 * ic + b, 0.0f);
    s1 = fmaxf(s1 * ic + b, 0.0f);
    s2 = fmaxf(s2 * ic + b, 0.0f);
    s3 = fmaxf(s3 * ic + b, 0.0f);
    if (half == 0) {
        f16x4 o;
        o.x = (f16)s0; o.y = (f16)s1; o.z = (f16)s2; o.w = (f16)s3;
        yout[(node << 5) | p] = o;
    }
}

// out[r,c] = b[c] + sum_n y3flat[r*NN + n] * Wout[c*NN + n]   (flat reinterpret view)
__global__ void out_kernel(const f16* __restrict__ y3, const float* __restrict__ Wout,
                           const float* __restrict__ bout, float* __restrict__ out) {
    int t = blockIdx.x;
    int sp = blockIdx.y;
    int tid = threadIdx.x;
    const int per = NN / NSPLIT;   // 12500
    int lo = sp * per;
    int hi = lo + per;
    float a0 = 0.0f, a1 = 0.0f, a2 = 0.0f;
    for (int n = lo + tid * 2; n < hi; n += 512) {
        f16x2 v2 = *(const f16x2*)(y3 + (size_t)t * NN + n);
        float vx = (float)v2.x, vy = (float)v2.y;
        float2 wA = *(const float2*)(Wout + n);
        float2 wB = *(const float2*)(Wout + NN + n);
        float2 wC = *(const float2*)(Wout + 2 * NN + n);
        a0 += vx * wA.x + vy * wA.y;
        a1 += vx * wB.x + vy * wB.y;
        a2 += vx * wC.x + vy * wC.y;
    }
    for (int o = 32; o > 0; o >>= 1) {
        a0 += __shfl_down(a0, o);
        a1 += __shfl_down(a1, o);
        a2 += __shfl_down(a2, o);
    }
    __shared__ float red[4][3];
    int wave = tid >> 6;
    if ((tid & 63) == 0) {
        red[wave][0] = a0;
        red[wave][1] = a1;
        red[wave][2] = a2;
    }
    __syncthreads();
    if (tid == 0) {
        float r0 = red[0][0] + red[1][0] + red[2][0] + red[3][0];
        float r1 = red[0][1] + red[1][1] + red[2][1] + red[3][1];
        float r2 = red[0][2] + red[1][2] + red[2][2] + red[3][2];
        if (sp == 0) {
            r0 += bout[0];
            r1 += bout[1];
            r2 += bout[2];
        }
        atomicAdd(&out[t * 3 + 0], r0);
        atomicAdd(&out[t * 3 + 1], r1);
        atomicAdd(&out[t * 3 + 2], r2);
    }
}

extern "C" void kernel_launch(void* const* d_in, const int* in_sizes, int n_in,
                              void* d_out, int out_size, void* d_ws, size_t ws_size,
                              hipStream_t stream) {
    const float* x    = (const float*)d_in[0];   // [N,T]
    const int*   ei   = (const int*)d_in[1];     // [2,E]
    const float* cw   = (const float*)d_in[2];   // [L,1,1,K]
    const float* cb   = (const float*)d_in[3];   // [L,1]
    const float* Wout = (const float*)d_in[4];   // [3,N]
    const float* bout = (const float*)d_in[5];   // [3]
    float* out = (float*)d_out;                  // [T,3]

    char* ws = (char*)d_ws;
    size_t off = 0;
    auto alloc = [&](size_t bytes) -> void* {
        void* p = ws + off;
        off += (bytes + 255) & ~(size_t)255;
        return p;
    };
    f16*          x16     = (f16*)alloc((size_t)NN * TT * 2);
    f16*          yA      = (f16*)alloc((size_t)NN * TT * 2);
    f16*          yB      = (f16*)alloc((size_t)NN * TT * 2);
    unsigned int* binned  = (unsigned int*)alloc((size_t)NBUCK * BCAP * 4);
    int*          gcursor = (int*)alloc((size_t)NBUCK * 4);
    int*          part    = (int*)alloc((size_t)NBUCK * 4);
    int*          offsets = (int*)alloc((size_t)(NN + 1) * 4);
    float*        inv_cnt = (float*)alloc((size_t)NN * 4);
    int*          col     = (int*)alloc((size_t)EE * 4);

    // CSR build (per call — ws is re-poisoned before every launch)
    hipMemsetAsync(gcursor, 0, (size_t)NBUCK * 4, stream);
    bin_kernel<<<(EE + 2047) / 2048, 256, 0, stream>>>(ei, gcursor, binned);
    scanpart_kernel<<<1, 256, 0, stream>>>(gcursor, part, offsets);
    bucket_csr_kernel<<<NBUCK, 256, 0, stream>>>(binned, gcursor, part, offsets, inv_cnt, col);

    // x -> fp16
    cvt_kernel<<<(NN * TT / 4 + 255) / 256, 256, 0, stream>>>((const float4*)x, (f16x4*)x16);

    // 3 fused layers (conv commuted past gather; bias/mean folded exactly)
    fused_layer_kernel<<<NN / 4, 256, 0, stream>>>((const f16x4*)x16, offsets, col, inv_cnt,
                                                   cw + 0 * KK, cb + 0, (f16x4*)yA);
    fused_layer_kernel<<<NN / 4, 256, 0, stream>>>((const f16x4*)yA, offsets, col, inv_cnt,
                                                   cw + 1 * KK, cb + 1, (f16x4*)yB);
    fused_layer_kernel<<<NN / 4, 256, 0, stream>>>((const f16x4*)yB, offsets, col, inv_cnt,
                                                   cw + 2 * KK, cb + 2, (f16x4*)yA);

    // output head (y3 = yA already has relu/mean applied)
    hipMemsetAsync(out, 0, (size_t)TT * 3 * 4, stream);
    out_kernel<<<dim3(TT, NSPLIT), 256, 0, stream>>>(yA, Wout, bout, out);
}